// Round 7
// baseline (54.445 us; speedup 1.0000x reference)
//
#include <hip/hip_runtime.h>
#include <math.h>

#define N0v 128
#define B1v 16
#define B2v 16
#define N1v 2048
#define N2v 32768
#define TOTALv 34944
#define BATCHv 1024
#define NEGV -100000000.0f

typedef __attribute__((ext_vector_type(4))) float f32x4;

// One block (1024 threads) per row. Header phase resolves pred0/pred1/S0/S1/
// Sg1/Sg2 from the 9KB out0+out1 prefix; out2 (128KB) streams through a
// depth-2 pipeline (load next / exp current / store current).
// Cache policy: input is read ONCE per pass -> non-temporal loads (no L3
// allocate); output (140MB, rewritten in place every replay) uses normal
// cached stores so it stays L3-resident and HBM write-back collapses.
__global__ __launch_bounds__(1024, 8) void row_kernel(
    const float* __restrict__ outs, const int* __restrict__ labels,
    float* __restrict__ out, float* __restrict__ partials)
{
    const int b   = blockIdx.x;
    const int tid = threadIdx.x;
    const int wid = tid >> 6, lane = tid & 63;
    const float* rowp = outs + (size_t)b * TOTALv;
    float*       orow = out  + (size_t)b * TOTALv;
    const f32x4* rv4 = reinterpret_cast<const f32x4*>(rowp);
    f32x4*       ov4 = reinterpret_cast<f32x4*>(orow);
    const f32x4  neg4 = {NEGV, NEGV, NEGV, NEGV};

    __shared__ float sm_gsum[128];
    __shared__ int   sm_gidx[128];
    __shared__ float s_wmax[2]; __shared__ int s_wmi[2];
    __shared__ float s_red[16][3];
    __shared__ int   s_i[2];
    __shared__ float s_loss[2];   // loss_partial, need_logS2 flag

    const int lab0 = labels[b * 3 + 0];
    const int lab1 = labels[b * 3 + 1];
    const int lab2 = labels[b * 3 + 2];

    // ---------------- header loads + first out2 chunk (all NT) ----------------
    float v0 = 0.f;
    if (tid < N0v) v0 = __builtin_nontemporal_load(&rowp[tid]);
    f32x4 a = {0.f, 0.f, 0.f, 0.f};
    if (tid < 512) a = __builtin_nontemporal_load(&rv4[32 + tid]);   // out1
    const f32x4* b2 = rv4 + 544;                   // out2: 8192 f4
    f32x4*       o2 = ov4 + 544;
    f32x4 cur = __builtin_nontemporal_load(&b2[tid]);
    float eg2 = 0.f;
    if (tid < 16) eg2 = rowp[N0v + N1v + lab1 * B2v + tid];
    float t0 = 0.f, t1 = 0.f, t2 = 0.f;
    if (tid == 0) { t0 = rowp[lab0]; t1 = rowp[N0v + lab1]; t2 = rowp[N0v + N1v + lab2]; }
    __builtin_amdgcn_sched_barrier(0);

    // ------- out1 (tid<512): exps + per-group(16) argmax & sumexp -------
    float s1 = 0.f;
    if (tid < 512) {
        s1 = __expf(a.x) + __expf(a.y) + __expf(a.z) + __expf(a.w);
        float gm = a.x; int gi = 0;
        if (a.y > gm) { gm = a.y; gi = 1; }
        if (a.z > gm) { gm = a.z; gi = 2; }
        if (a.w > gm) { gm = a.w; gi = 3; }
        gi += (tid & 3) * 4;
        float gs = s1;
        float ov = __shfl_xor(gm, 1); int oi = __shfl_xor(gi, 1);
        gs += __shfl_xor(gs, 1);
        if (ov > gm || (ov == gm && oi < gi)) { gm = ov; gi = oi; }
        ov = __shfl_xor(gm, 2); oi = __shfl_xor(gi, 2);
        gs += __shfl_xor(gs, 2);
        if (ov > gm || (ov == gm && oi < gi)) { gm = ov; gi = oi; }
        if ((tid & 3) == 0) { sm_gsum[tid >> 2] = gs; sm_gidx[tid >> 2] = gi; }
    }

    // ------- pred0: argmax over out0 (waves 0,1) -------
    if (tid < N0v) {
        float mv = v0; int mi = tid;
        #pragma unroll
        for (int off = 32; off; off >>= 1) {
            float ovv = __shfl_down(mv, off);
            int   oii = __shfl_down(mi, off);
            if (ovv > mv || (ovv == mv && oii < mi)) { mv = ovv; mi = oii; }
        }
        if (lane == 0) { s_wmax[wid] = mv; s_wmi[wid] = mi; }
    }

    // ------- Sg2: 16-wide sumexp at lab1 (lands in tid0 register) -------
    if (tid < 16) {
        eg2 = __expf(eg2);
        #pragma unroll
        for (int off = 8; off; off >>= 1) eg2 += __shfl_xor(eg2, off);
    }

    // ------- S0 (shiftless) + S1 wave reductions -------
    float r0 = (tid < N0v) ? __expf(v0) : 0.f;
    #pragma unroll
    for (int off = 32; off; off >>= 1) {
        r0 += __shfl_down(r0, off);
        s1 += __shfl_down(s1, off);
    }
    if (lane == 0) { s_red[wid][0] = r0; s_red[wid][1] = s1; }

    __syncthreads();   // barrier #1

    if (tid == 0) {
        float m0 = s_wmax[0]; int p0 = s_wmi[0];
        if (s_wmax[1] > m0 || (s_wmax[1] == m0 && s_wmi[1] < p0)) { m0 = s_wmax[1]; p0 = s_wmi[1]; }
        const int p1i = sm_gidx[p0];
        s_i[0] = p0; s_i[1] = p1i;
        float S0 = 0.f, S1 = 0.f;
        #pragma unroll
        for (int w = 0; w < 16; ++w) { S0 += s_red[w][0]; S1 += s_red[w][1]; }
        const float Sg1 = sm_gsum[lab0];
        const int r1 = lab1 - lab0 * B1v;
        const bool found0 = (p0 != lab0);
        const bool found1 = found0 || (p1i != r1);
        const float loss0 = __logf(S0) - t0;
        const float loss1 = (found0 ? __logf(S1) : __logf(Sg1)) - t1;
        s_loss[0] = loss0 + loss1 - t2 + (found1 ? 0.f : __logf(eg2));
        s_loss[1] = found1 ? 1.f : 0.f;
    }

    __syncthreads();   // barrier #2
    const int pred0 = s_i[0];
    const int pred1 = pred0 * B1v + s_i[1];

    // ------- out0/out1 masked stores (9KB, cached) -------
    if (tid < 512) {
        ov4[32 + tid] = ((tid >> 2) == pred0) ? a : neg4;
        if (tid < N0v) orow[tid] = v0;
    }

    // ------- out2 stream: depth-2 pipeline, 8 chunks (NT in, cached out) -------
    float s2 = 0.f;
    int idx = tid;
    #pragma unroll
    for (int it = 0; it < 7; ++it) {
        const f32x4 nxt = __builtin_nontemporal_load(&b2[idx + 1024]);
        s2 += __expf(cur.x) + __expf(cur.y) + __expf(cur.z) + __expf(cur.w);
        o2[idx] = ((idx >> 2) == pred1) ? cur : neg4;
        cur = nxt; idx += 1024;
    }
    s2 += __expf(cur.x) + __expf(cur.y) + __expf(cur.z) + __expf(cur.w);
    o2[idx] = ((idx >> 2) == pred1) ? cur : neg4;

    // ------- final S2 reduction -------
    #pragma unroll
    for (int off = 32; off; off >>= 1) s2 += __shfl_down(s2, off);
    if (lane == 0) s_red[wid][2] = s2;
    __syncthreads();   // barrier #3
    if (tid == 0) {
        float S2 = 0.f;
        #pragma unroll
        for (int w = 0; w < 16; ++w) S2 += s_red[w][2];
        partials[b] = s_loss[0] + s_loss[1] * __logf(S2);
    }
}

__global__ __launch_bounds__(256) void loss_reduce(
    const float* __restrict__ partials, float* __restrict__ out_loss)
{
    __shared__ float sh[4];
    const int tid = threadIdx.x;
    float s = 0.f;
    for (int i = tid; i < BATCHv; i += 256) s += partials[i];
    #pragma unroll
    for (int off = 32; off; off >>= 1) s += __shfl_down(s, off);
    if ((tid & 63) == 0) sh[tid >> 6] = s;
    __syncthreads();
    if (tid == 0) *out_loss = sh[0] + sh[1] + sh[2] + sh[3];
}

extern "C" void kernel_launch(void* const* d_in, const int* in_sizes, int n_in,
                              void* d_out, int out_size, void* d_ws, size_t ws_size,
                              hipStream_t stream) {
    const float* outs   = (const float*)d_in[0];
    const int*   labels = (const int*)d_in[1];
    float*       out    = (float*)d_out;
    float*       part   = (float*)d_ws;

    row_kernel<<<BATCHv, 1024, 0, stream>>>(outs, labels, out, part);
    loss_reduce<<<1, 256, 0, stream>>>(part, out + (size_t)BATCHv * TOTALv);
}

// Round 8
// 52.089 us; speedup vs baseline: 1.0452x; 1.0452x over previous
//
#include <hip/hip_runtime.h>
#include <math.h>

#define N0v 128
#define B1v 16
#define B2v 16
#define N1v 2048
#define N2v 32768
#define TOTALv 34944
#define BATCHv 1024
#define NEGV -100000000.0f

typedef __attribute__((ext_vector_type(4))) float f32x4;

// One block (1024 threads) per row. Store stream fully decoupled from load
// stream: NEG is NT-blasted over the entire out1+out2 region up-front (no
// dependencies -> write pipe saturates immediately); the input is stream-read
// for exp-sums only; after the single barrier pair, the two 64B pred-groups
// and out0 are (re)written. Barrier vmcnt-drain orders prefill vs overwrite.
__global__ __launch_bounds__(1024, 8) void row_kernel(
    const float* __restrict__ outs, const int* __restrict__ labels,
    float* __restrict__ out, float* __restrict__ partials)
{
    const int b   = blockIdx.x;
    const int tid = threadIdx.x;
    const int wid = tid >> 6, lane = tid & 63;
    const float* rowp = outs + (size_t)b * TOTALv;
    float*       orow = out  + (size_t)b * TOTALv;
    const f32x4* rv4 = reinterpret_cast<const f32x4*>(rowp);
    f32x4*       ov4 = reinterpret_cast<f32x4*>(orow);
    const f32x4  neg4 = {NEGV, NEGV, NEGV, NEGV};

    __shared__ float sm_gsum[128];
    __shared__ int   sm_gidx[128];
    __shared__ float s_wmax[2]; __shared__ int s_wmi[2];
    __shared__ float s_red[16][3];
    __shared__ int   s_i[2];

    const int lab0 = labels[b * 3 + 0];
    const int lab1 = labels[b * 3 + 1];
    const int lab2 = labels[b * 3 + 2];

    // ---------------- header loads + first out2 chunk ----------------
    float v0 = 0.f;
    if (tid < N0v) v0 = rowp[tid];
    f32x4 a = {0.f, 0.f, 0.f, 0.f};
    if (tid < 512) a = rv4[32 + tid];              // out1: f4 [32,544)
    const f32x4* b2 = rv4 + 544;                   // out2: 8192 f4
    f32x4*       o2 = ov4 + 544;
    f32x4 cur = b2[tid];                           // first stream chunk
    float eg2 = 0.f;
    if (tid < 16) eg2 = rowp[N0v + N1v + lab1 * B2v + tid];
    float t0 = 0.f, t1 = 0.f, t2 = 0.f;
    if (tid == 0) { t0 = rowp[lab0]; t1 = rowp[N0v + lab1]; t2 = rowp[N0v + N1v + lab2]; }

    // ---------------- NEG prefill: pure write stream, no deps ----------------
    if (tid < 512) __builtin_nontemporal_store(neg4, &ov4[32 + tid]);
    #pragma unroll
    for (int k = 0; k < 8; ++k)
        __builtin_nontemporal_store(neg4, &o2[tid + 1024 * k]);

    // ------- out1 (tid<512): exps + per-group(16) argmax & sumexp -------
    float s1 = 0.f;
    if (tid < 512) {
        s1 = __expf(a.x) + __expf(a.y) + __expf(a.z) + __expf(a.w);
        float gm = a.x; int gi = 0;
        if (a.y > gm) { gm = a.y; gi = 1; }
        if (a.z > gm) { gm = a.z; gi = 2; }
        if (a.w > gm) { gm = a.w; gi = 3; }
        gi += (tid & 3) * 4;
        float gs = s1;
        float ov = __shfl_xor(gm, 1); int oi = __shfl_xor(gi, 1);
        gs += __shfl_xor(gs, 1);
        if (ov > gm || (ov == gm && oi < gi)) { gm = ov; gi = oi; }
        ov = __shfl_xor(gm, 2); oi = __shfl_xor(gi, 2);
        gs += __shfl_xor(gs, 2);
        if (ov > gm || (ov == gm && oi < gi)) { gm = ov; gi = oi; }
        if ((tid & 3) == 0) { sm_gsum[tid >> 2] = gs; sm_gidx[tid >> 2] = gi; }
    }

    // ------- out0: copy store (only needs v0) + pred0 argmax -------
    if (tid < N0v) {
        __builtin_nontemporal_store(v0, &orow[tid]);
        float mv = v0; int mi = tid;
        #pragma unroll
        for (int off = 32; off; off >>= 1) {
            float ovv = __shfl_down(mv, off);
            int   oii = __shfl_down(mi, off);
            if (ovv > mv || (ovv == mv && oii < mi)) { mv = ovv; mi = oii; }
        }
        if (lane == 0) { s_wmax[wid] = mv; s_wmi[wid] = mi; }
    }

    // ------- Sg2: 16-wide sumexp at lab1 (lands in tid0 register) -------
    if (tid < 16) {
        eg2 = __expf(eg2);
        #pragma unroll
        for (int off = 8; off; off >>= 1) eg2 += __shfl_xor(eg2, off);
    }

    // ------- out2 stream: pure read + exp, depth-2, no stores -------
    float s2 = 0.f;
    {
        int idx = tid;
        #pragma unroll
        for (int it = 0; it < 7; ++it) {
            const f32x4 nxt = b2[idx + 1024];
            s2 += __expf(cur.x) + __expf(cur.y) + __expf(cur.z) + __expf(cur.w);
            cur = nxt; idx += 1024;
        }
        s2 += __expf(cur.x) + __expf(cur.y) + __expf(cur.z) + __expf(cur.w);
    }

    // ------- triple wave reduction (S0 shiftless, S1, S2) -------
    float r0 = (tid < N0v) ? __expf(v0) : 0.f;
    #pragma unroll
    for (int off = 32; off; off >>= 1) {
        r0 += __shfl_down(r0, off);
        s1 += __shfl_down(s1, off);
        s2 += __shfl_down(s2, off);
    }
    if (lane == 0) { s_red[wid][0] = r0; s_red[wid][1] = s1; s_red[wid][2] = s2; }

    __syncthreads();   // barrier #1 (also drains prefill stores)

    if (tid == 0) {
        float m0 = s_wmax[0]; int p0 = s_wmi[0];
        if (s_wmax[1] > m0 || (s_wmax[1] == m0 && s_wmi[1] < p0)) { m0 = s_wmax[1]; p0 = s_wmi[1]; }
        const int p1i = sm_gidx[p0];
        s_i[0] = p0; s_i[1] = p1i;
        float S0 = 0.f, S1 = 0.f, S2 = 0.f;
        #pragma unroll
        for (int w = 0; w < 16; ++w) { S0 += s_red[w][0]; S1 += s_red[w][1]; S2 += s_red[w][2]; }
        const float Sg1 = sm_gsum[lab0];
        const int r1 = lab1 - lab0 * B1v;
        const bool found0 = (p0 != lab0);
        const bool found1 = found0 || (p1i != r1);
        const float loss0 = __logf(S0) - t0;
        const float loss1 = (found0 ? __logf(S1) : __logf(Sg1)) - t1;
        const float loss2 = (found1 ? __logf(S2) : __logf(eg2)) - t2;
        partials[b] = loss0 + loss1 + loss2;
    }

    __syncthreads();   // barrier #2
    const int pred0 = s_i[0];
    const int pred1 = pred0 * B1v + s_i[1];

    // ------- group overwrites (64B each) -------
    if (tid < 512 && (tid >> 2) == pred0)
        __builtin_nontemporal_store(a, &ov4[32 + tid]);      // out1 group (from regs)
    if (tid < 4) {
        const f32x4 g = b2[pred1 * 4 + tid];                 // L2-hot reload
        __builtin_nontemporal_store(g, &o2[pred1 * 4 + tid]);
    }
}

__global__ __launch_bounds__(256) void loss_reduce(
    const float* __restrict__ partials, float* __restrict__ out_loss)
{
    __shared__ float sh[4];
    const int tid = threadIdx.x;
    float s = 0.f;
    for (int i = tid; i < BATCHv; i += 256) s += partials[i];
    #pragma unroll
    for (int off = 32; off; off >>= 1) s += __shfl_down(s, off);
    if ((tid & 63) == 0) sh[tid >> 6] = s;
    __syncthreads();
    if (tid == 0) *out_loss = sh[0] + sh[1] + sh[2] + sh[3];
}

extern "C" void kernel_launch(void* const* d_in, const int* in_sizes, int n_in,
                              void* d_out, int out_size, void* d_ws, size_t ws_size,
                              hipStream_t stream) {
    const float* outs   = (const float*)d_in[0];
    const int*   labels = (const int*)d_in[1];
    float*       out    = (float*)d_out;
    float*       part   = (float*)d_ws;

    row_kernel<<<BATCHv, 1024, 0, stream>>>(outs, labels, out, part);
    loss_reduce<<<1, 256, 0, stream>>>(part, out + (size_t)BATCHv * TOTALv);
}